// Round 6
// baseline (323.695 us; speedup 1.0000x reference)
//
#include <hip/hip_runtime.h>
#include <hip/hip_bf16.h>

// Biaffine: out[b,x,y] = Daug[b,x,:]·U·H[b,y,:] + Daug[b,x,:]·W1 + H[b,y,:]·W2
// B=32, S=512, d=1024.
// R6: single persistent fused kernel, 256 blocks (1/CU, forced by 160 KB LDS),
// block (b = bid%32, x = bid>>5) owns 64 rows.
//   phase 0: D-tile fp32->bf16 into LDS (XOR-swizzled) + linD reduction;
//            cast own 64-row H slice -> global Hbf; device-scope flag signal.
//   phase 1: T(64x1024) = Dls @ Ut + (U[d,:]+W2)  [linH folded into bias],
//            U dbuf-staged, ONE barrier/iter, T -> global scratch (bf16).
//   phase 2: out(64x512) = T @ Hbf[b]^T + linD, T+H dbuf-staged (144 KB).
// Cross-block dep (Hbf[b] from 8 same-XCD blocks) synced with device-scope
// atomics + bounded spin + idempotent self-cast fallback (no co-residency
// assumption needed for correctness).

#define D_DIM 1024
#define ROWS 16384

typedef float floatx4 __attribute__((ext_vector_type(4)));
typedef __bf16 bf16x8 __attribute__((ext_vector_type(8)));

__device__ inline unsigned short f2bf(float f) {
  unsigned int u = __builtin_bit_cast(unsigned int, f);
  u = (u + 0x7FFFu + ((u >> 16) & 1u)) >> 16;   // round-nearest-even
  return (unsigned short)u;
}

__device__ inline void async_load16(const void* g, void* l) {
  __builtin_amdgcn_global_load_lds(
      (const __attribute__((address_space(1))) void*)g,
      (__attribute__((address_space(3))) void*)l, 16, 0, 0);
}

__device__ inline bf16x8 cvt8(float4 a, float4 b) {
  union { bf16x8 v; __hip_bfloat162 h[4]; } u;
  u.h[0] = __float22bfloat162_rn(make_float2(a.x, a.y));
  u.h[1] = __float22bfloat162_rn(make_float2(a.z, a.w));
  u.h[2] = __float22bfloat162_rn(make_float2(b.x, b.y));
  u.h[3] = __float22bfloat162_rn(make_float2(b.z, b.w));
  return u.v;
}

// ---- prep: transpose U -> bf16 Ut[n][k], Ubias = U[d,:]+W2, zero flags -----
__global__ __launch_bounds__(256) void prep_kernel(
    const float* __restrict__ U, const float* __restrict__ W,
    unsigned short* __restrict__ Ut, float* __restrict__ Ubias,
    int* __restrict__ flags) {
  __shared__ float tile[32][33];
  int bid = blockIdx.x, tid = threadIdx.x;
  if (bid < 1024) {
    int n0 = (bid & 31) * 32, k0 = (bid >> 5) * 32;
    int tr = tid >> 5, tc = tid & 31;
    #pragma unroll
    for (int i = 0; i < 32; i += 8)
      tile[tr + i][tc] = U[(size_t)(k0 + tr + i) * D_DIM + n0 + tc];
    __syncthreads();
    #pragma unroll
    for (int i = 0; i < 32; i += 8)
      Ut[(size_t)(n0 + tr + i) * D_DIM + k0 + tc] = f2bf(tile[tc][tr + i]);
  } else if (bid < 1028) {
    int j = (bid - 1024) * 256 + tid;
    Ubias[j] = U[(size_t)D_DIM * D_DIM + j] + W[D_DIM + 1 + j];
  } else {
    if (tid < 32) flags[tid] = 0;
  }
}

// stage one U chunk (128n x 64k) for iter it: nc=it>>4, kc=it&15
// LDS chunk (n,q) at n*8 + (q^(n&7)); staging lanes hit 8x128B contiguous.
__device__ inline void stage_u(const unsigned short* __restrict__ Ut,
                               char* buf, int tid, int it) {
  int nc = it >> 4, kc = it & 15;
  #pragma unroll
  for (int i = 0; i < 4; ++i) {
    int idx = i * 256 + tid;
    int nl = idx >> 3, jj = idx & 7, q = jj ^ (nl & 7);
    async_load16(Ut + (size_t)(nc * 128 + nl) * D_DIM + kc * 64 + q * 8,
                 buf + idx * 16);
  }
}

// stage one phase-2 chunk: T(64m x 64k) + H(512y x 64k) for k-chunk k2
__device__ inline void stage_2(const unsigned short* __restrict__ Tblk,
                               const unsigned short* __restrict__ Hbf,
                               char* buf, int tid, int w, int l, int b, int k2) {
  #pragma unroll
  for (int i = 0; i < 2; ++i) {
    int idx = i * 256 + tid;
    int m = idx >> 3, jj = idx & 7, q = jj ^ (m & 7);
    async_load16(Tblk + (size_t)m * D_DIM + k2 * 64 + q * 8, buf + idx * 16);
  }
  int q = (l & 7) ^ (l >> 3);
  #pragma unroll
  for (int j = 0; j < 16; ++j) {
    int row = 32 * j + 8 * w + (l >> 3);
    async_load16(Hbf + ((size_t)b * 512 + row) * D_DIM + k2 * 64 + q * 8,
                 buf + 8192 + (j * 256 + tid) * 16);
  }
}

__global__ __launch_bounds__(256, 1) void fused_kernel(
    const float* __restrict__ D, const float* __restrict__ H,
    const float* __restrict__ W, const unsigned short* __restrict__ Ut,
    const float* __restrict__ Ubias, unsigned short* __restrict__ Hbf,
    unsigned short* __restrict__ Tbf, float* __restrict__ linDg,
    int* __restrict__ flags, float* __restrict__ out) {
  extern __shared__ char smem[];
  // phase 0/1 map: Dls [0,131072), Ub0 [131072,147456), Ub1 [147456,163840)
  // phase 2  map: Sb0 [0,73728), Sb1 [73728,147456)   (T 8 KB + H 64 KB each)
  unsigned short* Dls = (unsigned short*)smem;
  float* linD_lds = (float*)(smem + 131072);   // transient, inside Ub0
  char* Ub0 = smem + 131072;
  char* Ub1 = smem + 147456;
  int bid = blockIdx.x, tid = threadIdx.x;
  int b = bid & 31, x = bid >> 5;        // same-batch blocks: bid%8 const -> one XCD
  int l = tid & 63, w = tid >> 6;
  int quad = l >> 4, lrow = l & 15;
  size_t rowbase = (size_t)b * 512 + x * 64;

  // ---------------- phase 0: D -> LDS bf16 (+linD), H slice -> Hbf ----------
  if (tid < 64) linD_lds[tid] = W[D_DIM];
  __syncthreads();
  {
    int q = tid & 127, rh = tid >> 7;    // thread owns chunk q of rows 2j+rh
    float4 w0 = ((const float4*)(W + q * 8))[0];
    float4 w1 = ((const float4*)(W + q * 8))[1];
    #pragma unroll 4
    for (int j = 0; j < 32; ++j) {
      int row = 2 * j + rh;
      const float4* src = (const float4*)(D + (rowbase + row) * D_DIM + q * 8);
      float4 v0 = src[0], v1 = src[1];
      *(bf16x8*)(Dls + ((size_t)row * 128 + (q ^ (row & 7))) * 8) = cvt8(v0, v1);
      float s = v0.x * w0.x + v0.y * w0.y + v0.z * w0.z + v0.w * w0.w
              + v1.x * w1.x + v1.y * w1.y + v1.z * w1.z + v1.w * w1.w;
      #pragma unroll
      for (int off = 32; off > 0; off >>= 1) s += __shfl_down(s, off, 64);
      if (l == 0) atomicAdd(&linD_lds[row], s);
    }
    #pragma unroll 4
    for (int j = 0; j < 32; ++j) {
      int row = 2 * j + rh;
      const float4* src = (const float4*)(H + (rowbase + row) * D_DIM + q * 8);
      float4 v0 = src[0], v1 = src[1];
      *(bf16x8*)(Hbf + (rowbase + row) * D_DIM + q * 8) = cvt8(v0, v1);
    }
  }
  __threadfence();
  __syncthreads();                        // all Hbf stores + linD adds done
  if (tid == 0)
    __hip_atomic_fetch_add(&flags[b], 1, __ATOMIC_RELEASE, __HIP_MEMORY_SCOPE_AGENT);
  if (tid < 64) linDg[rowbase + tid] = linD_lds[tid];
  __syncthreads();                        // linD_lds read before Ub0 reuse

  // ---------------- phase 1: T = Dls @ Ut + Ubias -> Tblk (bf16) ------------
  unsigned short* Tblk = Tbf + (size_t)bid * (64 * D_DIM);
  floatx4 acc[4][2];
  stage_u(Ut, Ub0, tid, 0);
  for (int it = 0; it < 128; ++it) {
    int nc = it >> 4, kc = it & 15;
    __syncthreads();                      // drains prev prefetch (vmcnt) + LDS
    if (it + 1 < 128) stage_u(Ut, (it & 1) ? Ub0 : Ub1, tid, it + 1);
    if (kc == 0) {
      #pragma unroll
      for (int mt = 0; mt < 4; ++mt)
        #pragma unroll
        for (int nt = 0; nt < 2; ++nt)
          #pragma unroll
          for (int rr = 0; rr < 4; ++rr) acc[mt][nt][rr] = 0.f;
    }
    unsigned short* ub = (unsigned short*)((it & 1) ? Ub1 : Ub0);
    #pragma unroll
    for (int s = 0; s < 2; ++s) {
      int qg = kc * 8 + s * 4 + quad;
      bf16x8 a[4], bb[2];
      #pragma unroll
      for (int mt = 0; mt < 4; ++mt) {
        int m = mt * 16 + lrow;
        a[mt] = *(const bf16x8*)(Dls + ((size_t)m * 128 + (qg ^ (m & 7))) * 8);
      }
      #pragma unroll
      for (int nt = 0; nt < 2; ++nt) {
        int nl = w * 32 + nt * 16 + lrow;
        bb[nt] = *(const bf16x8*)(ub + ((size_t)nl * 8 + ((s * 4 + quad) ^ (nl & 7))) * 8);
      }
      #pragma unroll
      for (int mt = 0; mt < 4; ++mt)
        #pragma unroll
        for (int nt = 0; nt < 2; ++nt)
          acc[mt][nt] = __builtin_amdgcn_mfma_f32_16x16x32_bf16(
              a[mt], bb[nt], acc[mt][nt], 0, 0, 0);
    }
    if (kc == 15) {                       // n-chunk done: +bias, store T
      #pragma unroll
      for (int nt = 0; nt < 2; ++nt) {
        int col = nc * 128 + w * 32 + nt * 16 + lrow;
        float bias = Ubias[col];
        #pragma unroll
        for (int mt = 0; mt < 4; ++mt)
          #pragma unroll
          for (int rr = 0; rr < 4; ++rr)
            Tblk[(size_t)(mt * 16 + quad * 4 + rr) * D_DIM + col] =
                f2bf(acc[mt][nt][rr] + bias);
      }
    }
  }
  __syncthreads();                        // all waves done with Ub1/Dls

  // ---------------- sync: Hbf[b] fully written by 8 producer blocks ---------
  volatile int* ok = (int*)(smem + 150000);
  if (tid == 0) {
    int itc = 0;
    while (__hip_atomic_load(&flags[b], __ATOMIC_ACQUIRE, __HIP_MEMORY_SCOPE_AGENT) < 8
           && itc < 20000) { __builtin_amdgcn_s_sleep(8); ++itc; }
    *ok = (itc < 20000) ? 1 : 0;
  }
  __syncthreads();
  if (!*ok) {                             // fallback: cast all of H[b] ourselves
    int q = tid & 127, rh = tid >> 7;
    for (int j = 0; j < 256; ++j) {
      int row = 2 * j + rh;
      const float4* src = (const float4*)(H + ((size_t)b * 512 + row) * D_DIM + q * 8);
      float4 v0 = src[0], v1 = src[1];
      *(bf16x8*)(Hbf + ((size_t)b * 512 + row) * D_DIM + q * 8) = cvt8(v0, v1);
    }
    __threadfence();
    __syncthreads();
  }

  // ---------------- phase 2: out = T @ Hbf[b]^T + linD ----------------------
  floatx4 acc2[4][8] = {};
  char* Sb0 = smem;
  char* Sb1 = smem + 73728;
  stage_2(Tblk, Hbf, Sb0, tid, w, l, b, 0);
  for (int k2 = 0; k2 < 16; ++k2) {
    __syncthreads();
    if (k2 + 1 < 16) stage_2(Tblk, Hbf, (k2 & 1) ? Sb0 : Sb1, tid, w, l, b, k2 + 1);
    unsigned short* tb = (unsigned short*)((k2 & 1) ? Sb1 : Sb0);
    unsigned short* hb = tb + 4096;       // +8192 B
    #pragma unroll
    for (int s = 0; s < 2; ++s) {
      int q = s * 4 + quad;
      bf16x8 a[4], bb[8];
      #pragma unroll
      for (int mt = 0; mt < 4; ++mt) {
        int m = mt * 16 + lrow;
        a[mt] = *(const bf16x8*)(tb + ((size_t)m * 8 + (q ^ (m & 7))) * 8);
      }
      #pragma unroll
      for (int yt = 0; yt < 8; ++yt) {
        int y = w * 128 + yt * 16 + lrow;
        bb[yt] = *(const bf16x8*)(hb + ((size_t)y * 8 + (q ^ (y & 7))) * 8);
      }
      #pragma unroll
      for (int mt = 0; mt < 4; ++mt)
        #pragma unroll
        for (int yt = 0; yt < 8; ++yt)
          acc2[mt][yt] = __builtin_amdgcn_mfma_f32_16x16x32_bf16(
              a[mt], bb[yt], acc2[mt][yt], 0, 0, 0);
    }
  }
  #pragma unroll
  for (int mt = 0; mt < 4; ++mt) {
    float ld[4];
    #pragma unroll
    for (int rr = 0; rr < 4; ++rr)
      ld[rr] = linDg[rowbase + mt * 16 + quad * 4 + rr];
    #pragma unroll
    for (int yt = 0; yt < 8; ++yt) {
      int col = w * 128 + yt * 16 + lrow;
      #pragma unroll
      for (int rr = 0; rr < 4; ++rr)
        out[(rowbase + mt * 16 + quad * 4 + rr) * 512 + col] =
            acc2[mt][yt][rr] + ld[rr];
    }
  }
}

extern "C" void kernel_launch(void* const* d_in, const int* in_sizes, int n_in,
                              void* d_out, int out_size, void* d_ws, size_t ws_size,
                              hipStream_t stream) {
  const float* D = (const float*)d_in[0];
  const float* H = (const float*)d_in[1];
  const float* U = (const float*)d_in[2];   // [1025,1024]
  const float* W = (const float*)d_in[3];   // [2049]
  float* out = (float*)d_out;

  char* ws = (char*)d_ws;
  unsigned short* Hbf = (unsigned short*)ws; ws += (size_t)ROWS * D_DIM * 2;   // 32 MB
  unsigned short* Tbf = (unsigned short*)ws; ws += (size_t)ROWS * D_DIM * 2;   // 32 MB
  unsigned short* Ut  = (unsigned short*)ws; ws += (size_t)D_DIM * D_DIM * 2;  //  2 MB
  float* Ubias = (float*)ws;                 ws += (size_t)D_DIM * 4;
  float* linDg = (float*)ws;                 ws += (size_t)ROWS * 4;
  int* flags   = (int*)ws;                   ws += 128;

  prep_kernel<<<dim3(1029), 256, 0, stream>>>(U, W, Ut, Ubias, flags);
  hipFuncSetAttribute((const void*)fused_kernel,
                      hipFuncAttributeMaxDynamicSharedMemorySize, 163840);
  fused_kernel<<<dim3(256), 256, 163840, stream>>>(
      D, H, W, Ut, Ubias, Hbf, Tbf, linDg, flags, out);
}

// Round 7
// 226.039 us; speedup vs baseline: 1.4320x; 1.4320x over previous
//
#include <hip/hip_runtime.h>

// Biaffine: out[b,x,y] = Daug[b,x,:]·U·H[b,y,:] + Daug[b,x,:]·W1 + H[b,y,:]·W2
// B=32, S=512, d=1024.  bf16 MFMA two-stage GEMM:
//   T = D @ U[0:d,:] + (U[d,:] + W2)     (16384 x 1024 x 1024, bf16 out)
//        ^ linH = H·W2 folded into bias via Daug's ones-column
//   out[b] = T[b] @ H[b]^T + linD        (32 x 512x512x1024, fp32 out)
// R7 (back to R3 multi-kernel structure; R6 persistent 1-block/CU failed —
// Occupancy 11%, MfmaUtil 9%):
//   - cast: wave-per-row, 4 independent float4 loads, shuffle-only reduce
//   - GEMM K-loop: double-buffered LDS (BK=64, 64 KB), ONE barrier/iter —
//     stage(next) issued before compute(cur), so the barrier's vmcnt drain
//     finds loads already complete (prefetch distance = one MFMA phase)

#define D_DIM 1024
#define ROWS 16384   // B*S

typedef float floatx4 __attribute__((ext_vector_type(4)));
typedef __bf16 bf16x8 __attribute__((ext_vector_type(8)));

__device__ inline unsigned short f2bf(float f) {
  unsigned int u = __builtin_bit_cast(unsigned int, f);
  u = (u + 0x7FFFu + ((u >> 16) & 1u)) >> 16;   // round-nearest-even
  return (unsigned short)u;
}

__device__ inline ushort4 cvt4(float4 v) {
  ushort4 o;
  o.x = f2bf(v.x); o.y = f2bf(v.y); o.z = f2bf(v.z); o.w = f2bf(v.w);
  return o;
}

__device__ inline void async_load16(const void* g, void* l) {
  __builtin_amdgcn_global_load_lds(
      (const __attribute__((address_space(1))) void*)g,
      (__attribute__((address_space(3))) void*)l, 16, 0, 0);
}

// ---- prep: cast D/H -> bf16 (+linD), transpose U -> Ut, Ubias ---------------
// blocks [0,8192):    wave w<2: D row 2*bid+w (fused linD); w>=2: H row 2*bid+w-2
// blocks [8192,9216): U transpose tiles (32x32)
// blocks [9216,9220): Ubias[j] = U[d][j] + W[d+1+j]   (linH fold)
__global__ __launch_bounds__(256) void prep_kernel(
    const float* __restrict__ D, const float* __restrict__ H,
    const float* __restrict__ U, const float* __restrict__ W,
    unsigned short* __restrict__ Dbf, unsigned short* __restrict__ Hbf,
    unsigned short* __restrict__ Ut, float* __restrict__ Ubias,
    float* __restrict__ linD) {
  __shared__ float tile[32][33];
  int bid = blockIdx.x, tid = threadIdx.x;
  if (bid < 8192) {
    int w = tid >> 6, l = tid & 63;
    bool isH = w >= 2;
    int row = 2 * bid + (w & 1);
    const float* src = (isH ? H : D) + (size_t)row * D_DIM;
    // 4 independent loads in flight before any use
    float4 v0 = ((const float4*)src)[l];
    float4 v1 = ((const float4*)src)[l + 64];
    float4 v2 = ((const float4*)src)[l + 128];
    float4 v3 = ((const float4*)src)[l + 192];
    unsigned short* dst = (isH ? Hbf : Dbf) + (size_t)row * D_DIM;
    ((ushort4*)dst)[l]       = cvt4(v0);
    ((ushort4*)dst)[l + 64]  = cvt4(v1);
    ((ushort4*)dst)[l + 128] = cvt4(v2);
    ((ushort4*)dst)[l + 192] = cvt4(v3);
    if (!isH) {
      float4 w0 = ((const float4*)W)[l];
      float4 w1 = ((const float4*)W)[l + 64];
      float4 w2 = ((const float4*)W)[l + 128];
      float4 w3 = ((const float4*)W)[l + 192];
      float s = v0.x*w0.x + v0.y*w0.y + v0.z*w0.z + v0.w*w0.w
              + v1.x*w1.x + v1.y*w1.y + v1.z*w1.z + v1.w*w1.w
              + v2.x*w2.x + v2.y*w2.y + v2.z*w2.z + v2.w*w2.w
              + v3.x*w3.x + v3.y*w3.y + v3.z*w3.z + v3.w*w3.w;
      #pragma unroll
      for (int off = 32; off > 0; off >>= 1) s += __shfl_down(s, off, 64);
      if (l == 0) linD[row] = s + W[D_DIM];
    }
  } else if (bid < 9216) {
    int t = bid - 8192;
    int n0 = (t & 31) * 32, k0 = (t >> 5) * 32;
    int tr = tid >> 5, tc = tid & 31;
    #pragma unroll
    for (int i = 0; i < 32; i += 8)
      tile[tr + i][tc] = U[(size_t)(k0 + tr + i) * D_DIM + n0 + tc];
    __syncthreads();
    #pragma unroll
    for (int i = 0; i < 32; i += 8)
      Ut[(size_t)(n0 + tr + i) * D_DIM + k0 + tc] = f2bf(tile[tc][tr + i]);
  } else {
    int j = (bid - 9216) * 256 + tid;
    Ubias[j] = U[(size_t)D_DIM * D_DIM + j] + W[D_DIM + 1 + j];
  }
}

// ---- double-buffered swizzled MFMA K-loop core: 128x128 tile, BK=64 ---------
// LDS chunk (16B) for (row,q): c = (row>>3)*64 + (row&7)*8 + (q ^ (row&7)).
// Staging: 8 contiguous 128B global lines per instr, dest = base + lane*16.
// Frag reads conflict-free (verified R3: SQ_LDS_BANK_CONFLICT = 0).
__device__ inline void stage_tile(const unsigned short* gA, const unsigned short* gB,
                                  int k0, unsigned short* Ab, unsigned short* Bb,
                                  int tid) {
  #pragma unroll
  for (int j = 0; j < 4; ++j) {
    async_load16(gA + (size_t)(32 * j) * D_DIM + k0, Ab + (j * 256 + tid) * 8);
    async_load16(gB + (size_t)(32 * j) * D_DIM + k0, Bb + (j * 256 + tid) * 8);
  }
}

__device__ inline void gemm_core_dbuf(
    const unsigned short* __restrict__ A, const unsigned short* __restrict__ Bt,
    int m0, int n0, unsigned short* As0, unsigned short* Bs0,
    unsigned short* As1, unsigned short* Bs1, floatx4 (&acc)[4][4]) {
  const int K = D_DIM;
  int tid = threadIdx.x;
  int l = tid & 63, wave = tid >> 6;
  int quad = l >> 4, lrow = l & 15;
  int wm = wave >> 1, wn = wave & 1;

  int srow = 8 * wave + (l >> 3);
  int sq = (l & 7) ^ (l >> 3);
  const unsigned short* gA = A + (size_t)(m0 + srow) * K + sq * 8;
  const unsigned short* gB = Bt + (size_t)(n0 + srow) * K + sq * 8;

  int rl = lrow & 7, gofs = lrow >> 3;
  int baseA = wm * 512 + gofs * 64 + rl * 8;
  int baseB = wn * 512 + gofs * 64 + rl * 8;

  stage_tile(gA, gB, 0, As0, Bs0, tid);
  for (int k0 = 0; k0 < K; k0 += 64) {
    int par = (k0 >> 6) & 1;
    unsigned short* Ac = par ? As1 : As0;
    unsigned short* Bc = par ? Bs1 : Bs0;
    // barrier: drains stage(cur) (issued one compute-phase ago -> ~complete)
    // and protects next buffer against in-flight readers
    __syncthreads();
    if (k0 + 64 < K)
      stage_tile(gA, gB, k0 + 64, par ? As0 : As1, par ? Bs0 : Bs1, tid);
    #pragma unroll
    for (int s = 0; s < 2; ++s) {
      int xq = (s * 4 + quad) ^ rl;
      bf16x8 a[4], b[4];
      #pragma unroll
      for (int mt = 0; mt < 4; ++mt)
        a[mt] = *(const bf16x8*)(Ac + (baseA + mt * 128 + xq) * 8);
      #pragma unroll
      for (int nt = 0; nt < 4; ++nt)
        b[nt] = *(const bf16x8*)(Bc + (baseB + nt * 128 + xq) * 8);
      #pragma unroll
      for (int mt = 0; mt < 4; ++mt)
        #pragma unroll
        for (int nt = 0; nt < 4; ++nt)
          acc[mt][nt] = __builtin_amdgcn_mfma_f32_16x16x32_bf16(
              a[mt], b[nt], acc[mt][nt], 0, 0, 0);
    }
  }
}

// ---- GEMM1: T[m][n] = sum_k Dbf[m][k] * Ut[n][k] + Ubias[n], bf16 out -------
// grid (128, 8): blocks sharing A row-tile m are {m, m+128, ...} -> bid%8 =
// m%8 -> same XCD (A fetched once per XCD L2; verified FETCH 133->42 MB).
__global__ __launch_bounds__(256) void gemm1_kernel(
    const unsigned short* __restrict__ A,    // Dbf [16384,1024]
    const unsigned short* __restrict__ Bt,   // Ut  [1024,1024]
    const float* __restrict__ Ubias,         // fp32, len 1024 (incl. W2 fold)
    unsigned short* __restrict__ T) {
  __shared__ __align__(16) unsigned short As0[128 * 64];
  __shared__ __align__(16) unsigned short Bs0[128 * 64];
  __shared__ __align__(16) unsigned short As1[128 * 64];
  __shared__ __align__(16) unsigned short Bs1[128 * 64];
  int m0 = blockIdx.x * 128, n0 = blockIdx.y * 128;
  int tid = threadIdx.x;
  int lane = tid & 63, wave = tid >> 6;
  int quad = lane >> 4, lrow = lane & 15;
  int wm = wave >> 1, wn = wave & 1;

  floatx4 acc[4][4] = {};
  gemm_core_dbuf(A, Bt, m0, n0, As0, Bs0, As1, Bs1, acc);

  // C/D layout: col = lane&15, row = quad*4 + reg  [m89-verified]
  #pragma unroll
  for (int mt = 0; mt < 4; ++mt)
    #pragma unroll
    for (int nt = 0; nt < 4; ++nt) {
      int row = m0 + wm * 64 + mt * 16 + quad * 4;
      int col = n0 + wn * 64 + nt * 16 + lrow;
      float bias = Ubias[col];
      #pragma unroll
      for (int rr = 0; rr < 4; ++rr)
        T[(size_t)(row + rr) * D_DIM + col] = f2bf(acc[mt][nt][rr] + bias);
    }
}

// ---- GEMM2: out[b,x,y] = sum_k T[b,x,k]*Hbf[b,y,k] + linD[b,x] --------------
// grid (32, 16): batch b's blocks are {b, b+32, ...} -> bid%8 = b%8 -> same
// XCD; T[b]+H[b] = 4 MB ~ per-XCD L2.
__global__ __launch_bounds__(256) void gemm2_kernel(
    const unsigned short* __restrict__ Tg,   // [32*512,1024]
    const unsigned short* __restrict__ Hbf,  // [32*512,1024]
    const float* __restrict__ linD,
    float* __restrict__ out) {               // [32,512,512]
  __shared__ __align__(16) unsigned short As0[128 * 64];
  __shared__ __align__(16) unsigned short Bs0[128 * 64];
  __shared__ __align__(16) unsigned short As1[128 * 64];
  __shared__ __align__(16) unsigned short Bs1[128 * 64];
  int b = blockIdx.x;
  int t = blockIdx.y;
  int m0 = (t >> 2) * 128, n0 = (t & 3) * 128;
  const unsigned short* A = Tg + (size_t)b * 512 * D_DIM;
  const unsigned short* Bt = Hbf + (size_t)b * 512 * D_DIM;
  int tid = threadIdx.x;
  int lane = tid & 63, wave = tid >> 6;
  int quad = lane >> 4, lrow = lane & 15;
  int wm = wave >> 1, wn = wave & 1;

  floatx4 acc[4][4] = {};
  gemm_core_dbuf(A, Bt, m0, n0, As0, Bs0, As1, Bs1, acc);

  #pragma unroll
  for (int mt = 0; mt < 4; ++mt)
    #pragma unroll
    for (int nt = 0; nt < 4; ++nt) {
      int row = m0 + wm * 64 + mt * 16 + quad * 4;
      int col = n0 + wn * 64 + nt * 16 + lrow;
      #pragma unroll
      for (int rr = 0; rr < 4; ++rr) {
        float v = acc[mt][nt][rr] + linD[b * 512 + row + rr];
        out[((size_t)b * 512 + row + rr) * 512 + col] = v;
      }
    }
}

extern "C" void kernel_launch(void* const* d_in, const int* in_sizes, int n_in,
                              void* d_out, int out_size, void* d_ws, size_t ws_size,
                              hipStream_t stream) {
  const float* D = (const float*)d_in[0];
  const float* H = (const float*)d_in[1];
  const float* U = (const float*)d_in[2];   // [1025,1024]
  const float* W = (const float*)d_in[3];   // [2049]
  float* out = (float*)d_out;

  char* ws = (char*)d_ws;
  unsigned short* Dbf = (unsigned short*)ws; ws += (size_t)ROWS * D_DIM * 2;   // 32 MB
  unsigned short* Hbf = (unsigned short*)ws; ws += (size_t)ROWS * D_DIM * 2;   // 32 MB
  unsigned short* Tbf = (unsigned short*)ws; ws += (size_t)ROWS * D_DIM * 2;   // 32 MB
  unsigned short* Ut  = (unsigned short*)ws; ws += (size_t)D_DIM * D_DIM * 2;  //  2 MB
  float* Ubias = (float*)ws;                 ws += (size_t)D_DIM * 4;
  float* linD  = (float*)ws;                 ws += (size_t)ROWS * 4;

  prep_kernel<<<dim3(9220), 256, 0, stream>>>(D, H, U, W, Dbf, Hbf, Ut, Ubias, linD);
  gemm1_kernel<<<dim3(128, 8), 256, 0, stream>>>(Dbf, Ut, Ubias, Tbf);
  gemm2_kernel<<<dim3(32, 16), 256, 0, stream>>>(Tbf, Hbf, linD, out);
}